// Round 6
// baseline (176.243 us; speedup 1.0000x reference)
//
#include <hip/hip_runtime.h>

typedef __bf16 bf16;
typedef __bf16 bf16x8 __attribute__((ext_vector_type(8)));
typedef __bf16 bf16x4 __attribute__((ext_vector_type(4)));
typedef float  f32x4  __attribute__((ext_vector_type(4)));

#define SCALE 0.17677669529663687f  // 32^-0.5

// ws layout (bytes)
#define XWIN_OFF  0                  // bf16 [64][64][64][96]
#define WQKVT_OFF 50331648           // bf16 [288][96] (q cols pre-scaled)
#define WOUTT_OFF 50386944           // bf16 [96][96]  (transposed)
#define BIAS_OFF  50405376           // float [3][64][64]

// winattn dynamic-LDS layout (bytes); total 52512 -> 3 blocks/CU
#define L_QALL 0        // bf16 [64][96]
#define L_KALL 12288    // bf16 [64][96]; oall overlays after S(2)
#define L_SP   24576    // bf16 2 slots x [49][72] (tail reads spill into vt: harmless)
#define L_VT   38688    // bf16 [96][72]
#define L_FIN  24576    // f32 [49][101] overlays sp+vt after PV
#define L_TOTAL 52512
#define SP_SLOT 3528    // elements per slot (49*72)

// ---- fused im2win (blocks 0..511) + weight/bias prep (blocks 512..515)
__global__ __launch_bounds__(512)
void pre(const float* __restrict__ x, const float* __restrict__ wqkv,
         const float* __restrict__ pos, const float* __restrict__ wout,
         bf16* __restrict__ xwin, bf16* __restrict__ wqkvT,
         bf16* __restrict__ woutT, float* __restrict__ biasw)
{
    __shared__ bf16 xs[392 * 50];
    if (blockIdx.x < 512) {
        const int tid = threadIdx.x;
        const int b = blockIdx.x >> 3, wh = blockIdx.x & 7;
        const float* xb = x + (size_t)b * 96 * 3136 + wh * 7 * 56;
        bf16* xo = xwin + ((size_t)b * 64 + wh * 8) * 64 * 96;
        for (int c0 = 0; c0 < 96; c0 += 48) {
            if (c0) __syncthreads();
            for (int i = tid; i < 48 * 392; i += 512) {
                int c = i / 392, t = i - c * 392;
                xs[t * 50 + c] = (bf16)xb[(size_t)(c0 + c) * 3136 + t];
            }
            __syncthreads();
            for (int i = tid; i < 8 * 64 * 48; i += 512) {
                int c = i % 48;
                int wt = (i / 48) & 63;
                int win = i / (48 * 64);
                bf16 v = (bf16)0.f;
                if (wt < 49) v = xs[((wt / 7) * 56 + win * 7 + (wt % 7)) * 50 + c];
                xo[(win * 64 + wt) * 96 + c0 + c] = v;
            }
        }
    } else {
        int tid = (blockIdx.x - 512) * 512 + threadIdx.x;
        const int stride = 4 * 512;
        for (int i = tid; i < 288 * 96; i += stride) {
            int n = i / 96, c = i % 96;
            float v = wqkv[c * 288 + n];
            if (n < 96) v *= SCALE;
            wqkvT[i] = (bf16)v;
        }
        for (int i = tid; i < 96 * 96; i += stride) {
            int o = i / 96, c = i % 96;
            woutT[i] = (bf16)wout[c * 96 + o];
        }
        for (int i = tid; i < 3 * 64 * 64; i += stride) {
            int h = i >> 12, r = i & 4095, ii = r >> 6, j = r & 63;
            float v;
            if (j >= 49) v = -1e30f;
            else if (ii >= 49) v = 0.f;
            else {
                int ridx = ((j / 7) - (ii / 7) + 6) * 13 + ((j % 7) - (ii % 7) + 6);
                v = pos[ridx * 3 + h];
            }
            biasw[i] = v;
        }
    }
}

// One block per (batch, window). 512 threads = 8 waves.
// Waves 0-3: S+softmax engine. Waves 4-7: PV engine. Head-pipelined.
__global__ __launch_bounds__(512, 6)
void winattn(const bf16* __restrict__ xwin, const float* __restrict__ bout,
             const bf16* __restrict__ wqkvT, const bf16* __restrict__ woutT,
             const float* __restrict__ biasw, float* __restrict__ out)
{
    extern __shared__ __align__(16) unsigned char smem[];
    bf16* qall = (bf16*)(smem + L_QALL);
    bf16* kall = (bf16*)(smem + L_KALL);
    bf16* oall = (bf16*)(smem + L_KALL);
    bf16* sp   = (bf16*)(smem + L_SP);
    bf16* vt   = (bf16*)(smem + L_VT);
    float* fin = (float*)(smem + L_FIN);

    const int tid = threadIdx.x;
    const int lane = tid & 63;
    const int w  = tid >> 6;
    const int lr = lane & 15;
    const int lk = lane >> 4;

    const int blk = blockIdx.x;
    const int b = blk >> 6, win = blk & 63;
    const int row0 = (win >> 3) * 7, col0 = (win & 7) * 7;

    // proj bias prefetch (3 regs)
    float bo[3];
#pragma unroll
    for (int idx = 0; idx < 3; ++idx)
        bo[idx] = bout[(2 * idx + (w >> 2)) * 16 + lr];

    // ---- QKV: [64x96]@[96x288]; A-frags straight from global xwin
    const bf16* xg = xwin + (size_t)blk * 64 * 96;
    {
        const int mi = w & 3, nb = w >> 2;
        f32x4 acc[9];
#pragma unroll
        for (int i = 0; i < 9; ++i) acc[i] = (f32x4){0.f, 0.f, 0.f, 0.f};
#pragma unroll
        for (int k = 0; k < 3; ++k) {
            bf16x8 a = *(const bf16x8*)&xg[(mi * 16 + lr) * 96 + k * 32 + lk * 8];
#pragma unroll
            for (int idx = 0; idx < 9; ++idx) {
                int ni = 2 * idx + nb;
                bf16x8 bb = *(const bf16x8*)&wqkvT[(ni * 16 + lr) * 96 + k * 32 + lk * 8];
                acc[idx] = __builtin_amdgcn_mfma_f32_16x16x32_bf16(a, bb, acc[idx], 0, 0, 0);
            }
        }
#pragma unroll
        for (int idx = 0; idx < 9; ++idx) {
            int n0 = (2 * idx + nb) * 16;
            if (n0 < 96) {
#pragma unroll
                for (int e = 0; e < 4; ++e)
                    qall[(mi * 16 + lk * 4 + e) * 96 + n0 + lr] = (bf16)acc[idx][e];
            } else if (n0 < 192) {
#pragma unroll
                for (int e = 0; e < 4; ++e)
                    kall[(mi * 16 + lk * 4 + e) * 96 + n0 - 96 + lr] = (bf16)acc[idx][e];
            } else {
                int d = n0 - 192 + lr;
                bf16x4 pk;
                pk[0] = (bf16)acc[idx][0]; pk[1] = (bf16)acc[idx][1];
                pk[2] = (bf16)acc[idx][2]; pk[3] = (bf16)acc[idx][3];
                *(bf16x4*)&vt[d * 72 + mi * 16 + lk * 4] = pk;
            }
        }
    }

    // bias(head 0) prefetch for S-waves (overlaps barrier + S0 MFMA)
    const int smi = w & 3;
    float bias[4][4];
    if (w < 4) {
#pragma unroll
        for (int ni = 0; ni < 4; ++ni)
#pragma unroll
            for (int e = 0; e < 4; ++e)
                bias[ni][e] = biasw[(smi * 16 + lk * 4 + e) * 64 + ni * 16 + lr];
    }
    __syncthreads();

    f32x4 oacc[2][2];
#pragma unroll
    for (int hh = 0; hh < 2; ++hh)
#pragma unroll
        for (int ni = 0; ni < 2; ++ni)
            oacc[hh][ni] = (f32x4){0.f, 0.f, 0.f, 0.f};

    // ---- head pipeline: S(h) on w0-3; PV(h-1) on w4-7
#pragma unroll
    for (int h = 0; h < 3; ++h) {
        if (w < 4) {
            bf16x8 a = *(const bf16x8*)&qall[(smi * 16 + lr) * 96 + h * 32 + lk * 8];
            f32x4 sacc[4];
#pragma unroll
            for (int ni = 0; ni < 4; ++ni) {
                bf16x8 bb = *(const bf16x8*)&kall[(ni * 16 + lr) * 96 + h * 32 + lk * 8];
                f32x4 z = (f32x4){0.f, 0.f, 0.f, 0.f};
                sacc[ni] = __builtin_amdgcn_mfma_f32_16x16x32_bf16(a, bb, z, 0, 0, 0);
            }
#pragma unroll
            for (int ni = 0; ni < 4; ++ni)
#pragma unroll
                for (int e = 0; e < 4; ++e)
                    sacc[ni][e] += bias[ni][e];
            if (h < 2) {   // prefetch next head's bias (latency hidden by softmax)
#pragma unroll
                for (int ni = 0; ni < 4; ++ni)
#pragma unroll
                    for (int e = 0; e < 4; ++e)
                        bias[ni][e] = biasw[(h + 1) * 4096 + (smi * 16 + lk * 4 + e) * 64 + ni * 16 + lr];
            }
            bf16* spS = sp + (h & 1) * SP_SLOT;
#pragma unroll
            for (int e = 0; e < 4; ++e) {
                int row = smi * 16 + lk * 4 + e;
                float m = fmaxf(fmaxf(sacc[0][e], sacc[1][e]), fmaxf(sacc[2][e], sacc[3][e]));
                m = fmaxf(m, __shfl_xor(m, 1));
                m = fmaxf(m, __shfl_xor(m, 2));
                m = fmaxf(m, __shfl_xor(m, 4));
                m = fmaxf(m, __shfl_xor(m, 8));
                float p0 = __expf(sacc[0][e] - m), p1 = __expf(sacc[1][e] - m);
                float p2 = __expf(sacc[2][e] - m), p3 = __expf(sacc[3][e] - m);
                float s = (p0 + p1) + (p2 + p3);
                s += __shfl_xor(s, 1);
                s += __shfl_xor(s, 2);
                s += __shfl_xor(s, 4);
                s += __shfl_xor(s, 8);
                float inv = __builtin_amdgcn_rcpf(s);
                if (row < 49) {
                    bf16* pr = &spS[row * 72 + lr];
                    pr[0]  = (bf16)(p0 * inv);
                    pr[16] = (bf16)(p1 * inv);
                    pr[32] = (bf16)(p2 * inv);
                    pr[48] = (bf16)(p3 * inv);
                }
            }
        } else if (h >= 1) {
            const int hp = h - 1;
            const int mi = w - 4;
            const bf16* spS = sp + (hp & 1) * SP_SLOT;
#pragma unroll
            for (int ni = 0; ni < 2; ++ni)
#pragma unroll
                for (int kk = 0; kk < 2; ++kk) {
                    bf16x8 a  = *(const bf16x8*)&spS[(mi * 16 + lr) * 72 + kk * 32 + lk * 8];
                    bf16x8 bb = *(const bf16x8*)&vt[(hp * 32 + ni * 16 + lr) * 72 + kk * 32 + lk * 8];
                    oacc[hp][ni] = __builtin_amdgcn_mfma_f32_16x16x32_bf16(a, bb, oacc[hp][ni], 0, 0, 0);
                }
        }
        __syncthreads();
    }

    // ---- PV(head 2): all 8 waves, 1 tile each; then write O to LDS
    {
        const int mi2 = w >> 1, ni2 = w & 1;
        f32x4 o2 = (f32x4){0.f, 0.f, 0.f, 0.f};
#pragma unroll
        for (int kk = 0; kk < 2; ++kk) {
            bf16x8 a  = *(const bf16x8*)&sp[(mi2 * 16 + lr) * 72 + kk * 32 + lk * 8];
            bf16x8 bb = *(const bf16x8*)&vt[(64 + ni2 * 16 + lr) * 72 + kk * 32 + lk * 8];
            o2 = __builtin_amdgcn_mfma_f32_16x16x32_bf16(a, bb, o2, 0, 0, 0);
        }
#pragma unroll
        for (int e = 0; e < 4; ++e)
            oall[(mi2 * 16 + lk * 4 + e) * 96 + 64 + ni2 * 16 + lr] = (bf16)o2[e];
        if (w >= 4) {
            const int mi = w - 4;
#pragma unroll
            for (int hh = 0; hh < 2; ++hh)
#pragma unroll
                for (int ni = 0; ni < 2; ++ni)
#pragma unroll
                    for (int e = 0; e < 4; ++e)
                        oall[(mi * 16 + lk * 4 + e) * 96 + hh * 32 + ni * 16 + lr]
                            = (bf16)oacc[hh][ni][e];
        }
    }
    __syncthreads();

    // ---- proj: [64x96]@[96x96]+bias -> fin [49][101] f32
    {
        const int mi = w & 3, nb = w >> 2;
        f32x4 pacc[3];
#pragma unroll
        for (int i = 0; i < 3; ++i) pacc[i] = (f32x4){0.f, 0.f, 0.f, 0.f};
#pragma unroll
        for (int k = 0; k < 3; ++k) {
            bf16x8 a = *(const bf16x8*)&oall[(mi * 16 + lr) * 96 + k * 32 + lk * 8];
#pragma unroll
            for (int idx = 0; idx < 3; ++idx) {
                int ni = 2 * idx + nb;
                bf16x8 bb = *(const bf16x8*)&woutT[(ni * 16 + lr) * 96 + k * 32 + lk * 8];
                pacc[idx] = __builtin_amdgcn_mfma_f32_16x16x32_bf16(a, bb, pacc[idx], 0, 0, 0);
            }
        }
#pragma unroll
        for (int idx = 0; idx < 3; ++idx) {
            int n0 = (2 * idx + nb) * 16;
#pragma unroll
            for (int e = 0; e < 4; ++e) {
                int t = mi * 16 + lk * 4 + e;
                if (t < 49) fin[t * 101 + n0 + lr] = pacc[idx][e] + bo[idx];
            }
        }
    }
    __syncthreads();

    // ---- final store [b, c, H, W]
    for (int i = tid; i < 49 * 96; i += 512) {
        int c = i / 49, t = i - c * 49;
        out[((size_t)(b * 96 + c)) * 3136 + (row0 + t / 7) * 56 + col0 + t % 7]
            = fin[t * 101 + c];
    }
}

extern "C" void kernel_launch(void* const* d_in, const int* in_sizes, int n_in,
                              void* d_out, int out_size, void* d_ws, size_t ws_size,
                              hipStream_t stream) {
    const float* x    = (const float*)d_in[0];
    const float* wqkv = (const float*)d_in[1];
    const float* pos  = (const float*)d_in[2];
    const float* wout = (const float*)d_in[3];
    const float* bout = (const float*)d_in[4];
    float* outp = (float*)d_out;

    bf16*  xwin  = (bf16*)((char*)d_ws + XWIN_OFF);
    bf16*  wqkvT = (bf16*)((char*)d_ws + WQKVT_OFF);
    bf16*  woutT = (bf16*)((char*)d_ws + WOUTT_OFF);
    float* biasw = (float*)((char*)d_ws + BIAS_OFF);

    hipFuncSetAttribute((const void*)winattn,
                        hipFuncAttributeMaxDynamicSharedMemorySize, L_TOTAL);

    pre<<<dim3(516), dim3(512), 0, stream>>>(x, wqkv, pos, wout,
                                             xwin, wqkvT, woutT, biasw);
    winattn<<<dim3(4096), dim3(512), L_TOTAL, stream>>>(xwin, bout, wqkvT, woutT,
                                                        biasw, outp);
}

// Round 7
// 172.225 us; speedup vs baseline: 1.0233x; 1.0233x over previous
//
#include <hip/hip_runtime.h>

typedef __bf16 bf16;
typedef __bf16 bf16x4 __attribute__((ext_vector_type(4)));
typedef __bf16 bf16x8 __attribute__((ext_vector_type(8)));
typedef float  f32x4  __attribute__((ext_vector_type(4)));

#define SCALE 0.17677669529663687f  // 32^-0.5

// ws layout (bytes)
#define XWIN_OFF  0                  // bf16 [64 b][64 win][64 tok][96 ch]
#define WQKV2_OFF 50331648           // bf16 [3 h][96 rows: q0-31,k32-63,v64-95][96 ch]
#define WOUTT_OFF 50386944           // bf16 [96][96] transposed
#define BIAS_OFF  50405376           // f32  [3][64][64]

// per-wave LDS region (16384 B each, 4 waves = 64 KB static)
#define QOFF 0        // bf16 [64][40]
#define KOFF 5120     // bf16 [64][40]
#define VOFF 10240    // bf16 [32][72]
#define POFF 0        // bf16 [64][72]  overlays Q/K (dead after S reads)
#define OOFF 0        // bf16 [64][104] overlays all (after PV(2))
#define FOFF 0        // f32  [32][101] overlays Ost (after proj reads)

// ---- im2win (blocks 0..511) + weight/bias prep (blocks 512..515)
__global__ __launch_bounds__(512)
void pre(const float* __restrict__ x, const float* __restrict__ wqkv,
         const float* __restrict__ pos, const float* __restrict__ wout,
         bf16* __restrict__ xwin, bf16* __restrict__ wq2,
         bf16* __restrict__ woutT, float* __restrict__ biasw)
{
    __shared__ bf16 xs[392 * 50];
    if (blockIdx.x < 512) {
        const int tid = threadIdx.x;
        const int b = blockIdx.x >> 3, wh = blockIdx.x & 7;
        const float* xb = x + (size_t)b * 96 * 3136 + wh * 7 * 56;
        bf16* xo = xwin + ((size_t)b * 64 + wh * 8) * 64 * 96;
        for (int c0 = 0; c0 < 96; c0 += 48) {
            if (c0) __syncthreads();
            for (int i = tid; i < 48 * 392; i += 512) {
                int c = i / 392, t = i - c * 392;
                xs[t * 50 + c] = (bf16)xb[(size_t)(c0 + c) * 3136 + t];
            }
            __syncthreads();
            for (int i = tid; i < 8 * 64 * 48; i += 512) {
                int c = i % 48;
                int wt = (i / 48) & 63;
                int win = i / (48 * 64);
                bf16 v = (bf16)0.f;
                if (wt < 49) v = xs[((wt / 7) * 56 + win * 7 + (wt % 7)) * 50 + c];
                xo[(win * 64 + wt) * 96 + c0 + c] = v;
            }
        }
    } else {
        int tid = (blockIdx.x - 512) * 512 + threadIdx.x;
        const int stride = 4 * 512;
        // wq2[h][r][c]: r<32 q (scaled), 32-63 k, 64-95 v
        for (int i = tid; i < 3 * 96 * 96; i += stride) {
            int h = i / 9216, r = (i / 96) % 96, c = i % 96;
            int sel = r >> 5, d = r & 31;
            float v = wqkv[c * 288 + sel * 96 + h * 32 + d];
            if (sel == 0) v *= SCALE;
            wq2[i] = (bf16)v;
        }
        for (int i = tid; i < 96 * 96; i += stride) {
            int o = i / 96, c = i % 96;
            woutT[i] = (bf16)wout[c * 96 + o];
        }
        for (int i = tid; i < 3 * 64 * 64; i += stride) {
            int h = i >> 12, r = i & 4095, ii = r >> 6, j = r & 63;
            float v;
            if (j >= 49) v = -1e30f;
            else if (ii >= 49) v = 0.f;
            else {
                int ridx = ((j / 7) - (ii / 7) + 6) * 13 + ((j % 7) - (ii % 7) + 6);
                v = pos[ridx * 3 + h];
            }
            biasw[i] = v;
        }
    }
}

__device__ __forceinline__ void head_step(
    int h, const bf16* __restrict__ xg, const bf16* __restrict__ wq2,
    const float* __restrict__ biasw,
    bf16* Q, bf16* K, bf16* Vt, bf16* P,
    int lr, int lk, f32x4 (&oacc)[4][2])
{
    // ---- QKV for this head: [64x96]@[96x96], 24 tiles in 2 ni-groups of 3
#pragma unroll
    for (int g = 0; g < 2; ++g) {
        f32x4 acc[4][3];
#pragma unroll
        for (int mi = 0; mi < 4; ++mi)
#pragma unroll
            for (int nj = 0; nj < 3; ++nj) acc[mi][nj] = (f32x4){0.f, 0.f, 0.f, 0.f};
#pragma unroll
        for (int k = 0; k < 3; ++k) {
            bf16x8 a[4];
#pragma unroll
            for (int mi = 0; mi < 4; ++mi)
                a[mi] = *(const bf16x8*)&xg[(mi * 16 + lr) * 96 + k * 32 + lk * 8];
#pragma unroll
            for (int nj = 0; nj < 3; ++nj) {
                int ni = g * 3 + nj;
                bf16x8 wb = *(const bf16x8*)&wq2[(h * 96 + ni * 16 + lr) * 96 + k * 32 + lk * 8];
#pragma unroll
                for (int mi = 0; mi < 4; ++mi)
                    acc[mi][nj] = __builtin_amdgcn_mfma_f32_16x16x32_bf16(a[mi], wb, acc[mi][nj], 0, 0, 0);
            }
        }
#pragma unroll
        for (int nj = 0; nj < 3; ++nj) {
            int ni = g * 3 + nj;
#pragma unroll
            for (int mi = 0; mi < 4; ++mi) {
                if (ni < 2) {
#pragma unroll
                    for (int e = 0; e < 4; ++e)
                        Q[(mi * 16 + lk * 4 + e) * 40 + ni * 16 + lr] = (bf16)acc[mi][nj][e];
                } else if (ni < 4) {
#pragma unroll
                    for (int e = 0; e < 4; ++e)
                        K[(mi * 16 + lk * 4 + e) * 40 + (ni - 2) * 16 + lr] = (bf16)acc[mi][nj][e];
                } else {
                    bf16x4 pk;
#pragma unroll
                    for (int e = 0; e < 4; ++e) pk[e] = (bf16)acc[mi][nj][e];
                    *(bf16x4*)&Vt[((ni - 4) * 16 + lr) * 72 + mi * 16 + lk * 4] = pk;
                }
            }
        }
    }
    asm volatile("s_waitcnt lgkmcnt(0)" ::: "memory");

    // ---- S = Q@K^T: 16 tiles into regs
    f32x4 sacc[4][4];
    bf16x8 kb[4];
#pragma unroll
    for (int ni = 0; ni < 4; ++ni)
        kb[ni] = *(const bf16x8*)&K[(ni * 16 + lr) * 40 + lk * 8];
#pragma unroll
    for (int mi = 0; mi < 4; ++mi) {
        bf16x8 qa = *(const bf16x8*)&Q[(mi * 16 + lr) * 40 + lk * 8];
#pragma unroll
        for (int ni = 0; ni < 4; ++ni) {
            f32x4 z = (f32x4){0.f, 0.f, 0.f, 0.f};
            sacc[mi][ni] = __builtin_amdgcn_mfma_f32_16x16x32_bf16(qa, kb[ni], z, 0, 0, 0);
        }
    }
    // ---- bias + softmax (rows owned by 16-lane lr groups) + P write (overlays Q/K)
#pragma unroll
    for (int mi = 0; mi < 4; ++mi) {
#pragma unroll
        for (int e = 0; e < 4; ++e) {
            int row = mi * 16 + lk * 4 + e;
            float s0 = sacc[mi][0][e] + biasw[h * 4096 + row * 64 + lr];
            float s1 = sacc[mi][1][e] + biasw[h * 4096 + row * 64 + 16 + lr];
            float s2 = sacc[mi][2][e] + biasw[h * 4096 + row * 64 + 32 + lr];
            float s3 = sacc[mi][3][e] + biasw[h * 4096 + row * 64 + 48 + lr];
            float m = fmaxf(fmaxf(s0, s1), fmaxf(s2, s3));
            m = fmaxf(m, __shfl_xor(m, 1));
            m = fmaxf(m, __shfl_xor(m, 2));
            m = fmaxf(m, __shfl_xor(m, 4));
            m = fmaxf(m, __shfl_xor(m, 8));
            float p0 = __expf(s0 - m), p1 = __expf(s1 - m);
            float p2 = __expf(s2 - m), p3 = __expf(s3 - m);
            float s = (p0 + p1) + (p2 + p3);
            s += __shfl_xor(s, 1);
            s += __shfl_xor(s, 2);
            s += __shfl_xor(s, 4);
            s += __shfl_xor(s, 8);
            float inv = __builtin_amdgcn_rcpf(s);
            P[row * 72 + lr]      = (bf16)(p0 * inv);
            P[row * 72 + 16 + lr] = (bf16)(p1 * inv);
            P[row * 72 + 32 + lr] = (bf16)(p2 * inv);
            P[row * 72 + 48 + lr] = (bf16)(p3 * inv);
        }
    }
    asm volatile("s_waitcnt lgkmcnt(0)" ::: "memory");

    // ---- PV: O_h += P @ V_h, accumulate in regs
    bf16x8 vb[2][2];
#pragma unroll
    for (int ni = 0; ni < 2; ++ni)
#pragma unroll
        for (int kk = 0; kk < 2; ++kk)
            vb[ni][kk] = *(const bf16x8*)&Vt[(ni * 16 + lr) * 72 + kk * 32 + lk * 8];
#pragma unroll
    for (int mi = 0; mi < 4; ++mi) {
#pragma unroll
        for (int kk = 0; kk < 2; ++kk) {
            bf16x8 pa = *(const bf16x8*)&P[(mi * 16 + lr) * 72 + kk * 32 + lk * 8];
#pragma unroll
            for (int ni = 0; ni < 2; ++ni)
                oacc[mi][ni] = __builtin_amdgcn_mfma_f32_16x16x32_bf16(pa, vb[ni][kk], oacc[mi][ni], 0, 0, 0);
        }
    }
}

// One WAVE per window; 4 independent waves per block; zero __syncthreads.
__global__ __launch_bounds__(256, 2)
void winattn(const bf16* __restrict__ xwin, const float* __restrict__ bout,
             const bf16* __restrict__ wq2, const bf16* __restrict__ woutT,
             const float* __restrict__ biasw, float* __restrict__ out)
{
    __shared__ __align__(16) unsigned char smem[65536];
    const int tid = threadIdx.x;
    const int w = tid >> 6, lane = tid & 63;
    const int lr = lane & 15, lk = lane >> 4;
    unsigned char* base = smem + w * 16384;
    bf16* Q  = (bf16*)(base + QOFF);
    bf16* K  = (bf16*)(base + KOFF);
    bf16* Vt = (bf16*)(base + VOFF);
    bf16* P  = (bf16*)(base + POFF);

    const int g = blockIdx.x * 4 + w;
    const int b = g >> 6, widx = g & 63;
    const int row0 = (widx >> 3) * 7, col0 = (widx & 7) * 7;
    const bf16* xg = xwin + (size_t)g * 64 * 96;

    float bo[6];
#pragma unroll
    for (int ni = 0; ni < 6; ++ni) bo[ni] = bout[ni * 16 + lr];

    f32x4 oacc0[4][2], oacc1[4][2], oacc2[4][2];
#pragma unroll
    for (int mi = 0; mi < 4; ++mi)
#pragma unroll
        for (int ni = 0; ni < 2; ++ni) {
            oacc0[mi][ni] = (f32x4){0.f, 0.f, 0.f, 0.f};
            oacc1[mi][ni] = (f32x4){0.f, 0.f, 0.f, 0.f};
            oacc2[mi][ni] = (f32x4){0.f, 0.f, 0.f, 0.f};
        }

    head_step(0, xg, wq2, biasw, Q, K, Vt, P, lr, lk, oacc0);
    head_step(1, xg, wq2, biasw, Q, K, Vt, P, lr, lk, oacc1);
    head_step(2, xg, wq2, biasw, Q, K, Vt, P, lr, lk, oacc2);

    // ---- O -> LDS [64][104] bf16 (overlays everything; all prior reads done)
    bf16* Ost = (bf16*)(base + OOFF);
#pragma unroll
    for (int mi = 0; mi < 4; ++mi)
#pragma unroll
        for (int ni = 0; ni < 2; ++ni)
#pragma unroll
            for (int e = 0; e < 4; ++e) {
                int row = mi * 16 + lk * 4 + e;
                Ost[row * 104 +      ni * 16 + lr] = (bf16)oacc0[mi][ni][e];
                Ost[row * 104 + 32 + ni * 16 + lr] = (bf16)oacc1[mi][ni][e];
                Ost[row * 104 + 64 + ni * 16 + lr] = (bf16)oacc2[mi][ni][e];
            }
    asm volatile("s_waitcnt lgkmcnt(0)" ::: "memory");

    // ---- proj: [64x96]@[96x96]
    f32x4 pacc[4][6];
#pragma unroll
    for (int mi = 0; mi < 4; ++mi)
#pragma unroll
        for (int ni = 0; ni < 6; ++ni) pacc[mi][ni] = (f32x4){0.f, 0.f, 0.f, 0.f};
#pragma unroll
    for (int k = 0; k < 3; ++k) {
        bf16x8 a[4];
#pragma unroll
        for (int mi = 0; mi < 4; ++mi)
            a[mi] = *(const bf16x8*)&Ost[(mi * 16 + lr) * 104 + k * 32 + lk * 8];
#pragma unroll
        for (int ni = 0; ni < 6; ++ni) {
            bf16x8 wb = *(const bf16x8*)&woutT[(ni * 16 + lr) * 96 + k * 32 + lk * 8];
#pragma unroll
            for (int mi = 0; mi < 4; ++mi)
                pacc[mi][ni] = __builtin_amdgcn_mfma_f32_16x16x32_bf16(a[mi], wb, pacc[mi][ni], 0, 0, 0);
        }
    }

    // ---- store via 2-pass f32 LDS staging (coalesced-ish 7-float runs)
    float* fin = (float*)(base + FOFF);
#pragma unroll
    for (int p = 0; p < 2; ++p) {
        const int nr = p ? 17 : 32;
#pragma unroll
        for (int mm = 0; mm < 2; ++mm) {
            int mi = p * 2 + mm;
#pragma unroll
            for (int ni = 0; ni < 6; ++ni)
#pragma unroll
                for (int e = 0; e < 4; ++e) {
                    int t = mi * 16 + lk * 4 + e;
                    int tl = t - p * 32;
                    if (tl >= 0 && tl < nr)
                        fin[tl * 101 + ni * 16 + lr] = pacc[mi][ni][e] + bo[ni];
                }
        }
        asm volatile("s_waitcnt lgkmcnt(0)" ::: "memory");
        for (int j = lane; j < 96 * nr; j += 64) {
            int c = j / nr, tl = j - c * nr;
            int t = p * 32 + tl;
            out[((size_t)(b * 96 + c)) * 3136 + (row0 + t / 7) * 56 + col0 + t % 7]
                = fin[tl * 101 + c];
        }
    }
}

extern "C" void kernel_launch(void* const* d_in, const int* in_sizes, int n_in,
                              void* d_out, int out_size, void* d_ws, size_t ws_size,
                              hipStream_t stream) {
    const float* x    = (const float*)d_in[0];
    const float* wqkv = (const float*)d_in[1];
    const float* pos  = (const float*)d_in[2];
    const float* wout = (const float*)d_in[3];
    const float* bout = (const float*)d_in[4];
    float* outp = (float*)d_out;

    bf16*  xwin  = (bf16*)((char*)d_ws + XWIN_OFF);
    bf16*  wq2   = (bf16*)((char*)d_ws + WQKV2_OFF);
    bf16*  woutT = (bf16*)((char*)d_ws + WOUTT_OFF);
    float* biasw = (float*)((char*)d_ws + BIAS_OFF);

    pre<<<dim3(516), dim3(512), 0, stream>>>(x, wqkv, pos, wout,
                                             xwin, wq2, woutT, biasw);
    winattn<<<dim3(1024), dim3(256), 0, stream>>>(xwin, bout, wq2, woutT,
                                                  biasw, outp);
}

// Round 8
// 150.902 us; speedup vs baseline: 1.1679x; 1.1413x over previous
//
#include <hip/hip_runtime.h>

typedef __bf16 bf16;
typedef __bf16 bf16x4 __attribute__((ext_vector_type(4)));
typedef __bf16 bf16x8 __attribute__((ext_vector_type(8)));
typedef float  f32x4  __attribute__((ext_vector_type(4)));

#define SCALE 0.17677669529663687f  // 32^-0.5

// ws layout (bytes)
#define XWIN_OFF  0                  // bf16 [64 b][64 win][64 tok][96 ch]
#define WQKVT_OFF 50331648           // bf16 [288][96] (q cols pre-scaled)
#define WOUTT_OFF 50386944           // bf16 [96][96] transposed
#define BIAS_OFF  50405376           // f32  [3][64][64]

// ---- im2win (blocks 0..511) + weight/bias prep (blocks 512..515)
__global__ __launch_bounds__(512)
void pre(const float* __restrict__ x, const float* __restrict__ wqkv,
         const float* __restrict__ pos, const float* __restrict__ wout,
         bf16* __restrict__ xwin, bf16* __restrict__ wqkvT,
         bf16* __restrict__ woutT, float* __restrict__ biasw)
{
    __shared__ bf16 xs[392 * 50];
    if (blockIdx.x < 512) {
        const int tid = threadIdx.x;
        const int b = blockIdx.x >> 3, wh = blockIdx.x & 7;
        const float* xb = x + (size_t)b * 96 * 3136 + wh * 7 * 56;
        bf16* xo = xwin + ((size_t)b * 64 + wh * 8) * 64 * 96;
        for (int c0 = 0; c0 < 96; c0 += 48) {
            if (c0) __syncthreads();
            for (int i = tid; i < 48 * 392; i += 512) {
                int c = i / 392, t = i - c * 392;
                xs[t * 50 + c] = (bf16)xb[(size_t)(c0 + c) * 3136 + t];
            }
            __syncthreads();
            for (int i = tid; i < 8 * 64 * 48; i += 512) {
                int c = i % 48;
                int wt = (i / 48) & 63;
                int win = i / (48 * 64);
                bf16 v = (bf16)0.f;
                if (wt < 49) v = xs[((wt / 7) * 56 + win * 7 + (wt % 7)) * 50 + c];
                xo[(win * 64 + wt) * 96 + c0 + c] = v;
            }
        }
    } else {
        int tid = (blockIdx.x - 512) * 512 + threadIdx.x;
        const int stride = 4 * 512;
        for (int i = tid; i < 288 * 96; i += stride) {
            int n = i / 96, c = i % 96;
            float v = wqkv[c * 288 + n];
            if (n < 96) v *= SCALE;
            wqkvT[i] = (bf16)v;
        }
        for (int i = tid; i < 96 * 96; i += stride) {
            int o = i / 96, c = i % 96;
            woutT[i] = (bf16)wout[c * 96 + o];
        }
        for (int i = tid; i < 3 * 64 * 64; i += stride) {
            int h = i >> 12, r = i & 4095, ii = r >> 6, j = r & 63;
            float v;
            if (j >= 49) v = -1e30f;
            else if (ii >= 49) v = 0.f;
            else {
                int ridx = ((j / 7) - (ii / 7) + 6) * 13 + ((j % 7) - (ii % 7) + 6);
                v = pos[ridx * 3 + h];
            }
            biasw[i] = v;
        }
    }
}

// One block (4 waves, 256 thr) per window. Wave w owns token strip w*16..+15.
// Attention core (S+softmax+PV) is wave-local: zero barriers inside.
// 3 __syncthreads total. LDS 49664 B -> 3 blocks/CU.
__global__ __launch_bounds__(256, 3)
void winattn(const bf16* __restrict__ xwin, const float* __restrict__ bout,
             const bf16* __restrict__ wqkvT, const bf16* __restrict__ woutT,
             const float* __restrict__ biasw, float* __restrict__ out)
{
    __shared__ __align__(16) unsigned char smem[49664];
    bf16* qall = (bf16*)(smem);          // [64][104]
    bf16* kall = (bf16*)(smem + 13312);  // [64][104]
    bf16* vt   = (bf16*)(smem + 26624);  // [96][72]  v transposed
    bf16* Pp   = (bf16*)(smem + 40448);  // 4 x [16][72] private P slices
    bf16* Ost  = (bf16*)(smem);          // overlay qall (per-strip, in-wave safe)
    float* fin = (float*)(smem + 13312); // [64][101] overlay kall+vt

    const int tid = threadIdx.x;
    const int w = tid >> 6, lane = tid & 63;
    const int lr = lane & 15, lk = lane >> 4;

    const int blk = blockIdx.x;
    const int b = blk >> 6, win = blk & 63;
    const int row0 = (win >> 3) * 7, col0 = (win & 7) * 7;
    const bf16* xg = xwin + (size_t)blk * 64 * 96;

    float bo[6];
#pragma unroll
    for (int ni = 0; ni < 6; ++ni) bo[ni] = bout[ni * 16 + lr];

    // ---- QKV: wave w owns row strip mi=w; all 18 ni tiles. 54 MFMA/wave.
    {
        bf16x8 a[3];
#pragma unroll
        for (int k = 0; k < 3; ++k)
            a[k] = *(const bf16x8*)&xg[(w * 16 + lr) * 96 + k * 32 + lk * 8];
        f32x4 acc[18];
#pragma unroll
        for (int ni = 0; ni < 18; ++ni) acc[ni] = (f32x4){0.f, 0.f, 0.f, 0.f};
#pragma unroll
        for (int k = 0; k < 3; ++k)
#pragma unroll
            for (int ni = 0; ni < 18; ++ni) {
                bf16x8 bb = *(const bf16x8*)&wqkvT[(ni * 16 + lr) * 96 + k * 32 + lk * 8];
                acc[ni] = __builtin_amdgcn_mfma_f32_16x16x32_bf16(a[k], bb, acc[ni], 0, 0, 0);
            }
#pragma unroll
        for (int ni = 0; ni < 6; ++ni)
#pragma unroll
            for (int e = 0; e < 4; ++e)
                qall[(w * 16 + lk * 4 + e) * 104 + ni * 16 + lr] = (bf16)acc[ni][e];
#pragma unroll
        for (int ni = 6; ni < 12; ++ni)
#pragma unroll
            for (int e = 0; e < 4; ++e)
                kall[(w * 16 + lk * 4 + e) * 104 + (ni - 6) * 16 + lr] = (bf16)acc[ni][e];
#pragma unroll
        for (int ni = 12; ni < 18; ++ni) {
            bf16x4 pk;
#pragma unroll
            for (int e = 0; e < 4; ++e) pk[e] = (bf16)acc[ni][e];
            *(bf16x4*)&vt[((ni - 12) * 16 + lr) * 72 + w * 16 + lk * 4] = pk;
        }
    }
    __syncthreads();

    // ---- per-head S + softmax + PV, fully wave-local on strip w
    f32x4 oacc[3][2];
#pragma unroll
    for (int h = 0; h < 3; ++h)
#pragma unroll
        for (int ni = 0; ni < 2; ++ni) oacc[h][ni] = (f32x4){0.f, 0.f, 0.f, 0.f};
    bf16* Pw = Pp + w * 1152;   // [16][72]

#pragma unroll
    for (int h = 0; h < 3; ++h) {
        // S = Qstrip @ K^T  (4 MFMA)
        bf16x8 qa = *(const bf16x8*)&qall[(w * 16 + lr) * 104 + h * 32 + lk * 8];
        f32x4 sacc[4];
#pragma unroll
        for (int ni = 0; ni < 4; ++ni) {
            bf16x8 kb = *(const bf16x8*)&kall[(ni * 16 + lr) * 104 + h * 32 + lk * 8];
            f32x4 z = (f32x4){0.f, 0.f, 0.f, 0.f};
            sacc[ni] = __builtin_amdgcn_mfma_f32_16x16x32_bf16(qa, kb, z, 0, 0, 0);
        }
        // bias + softmax (rows in lk*4+e; cols across lr x ni)
#pragma unroll
        for (int e = 0; e < 4; ++e) {
            int row = w * 16 + lk * 4 + e;
            float s0 = sacc[0][e] + biasw[h * 4096 + row * 64 + lr];
            float s1 = sacc[1][e] + biasw[h * 4096 + row * 64 + 16 + lr];
            float s2 = sacc[2][e] + biasw[h * 4096 + row * 64 + 32 + lr];
            float s3 = sacc[3][e] + biasw[h * 4096 + row * 64 + 48 + lr];
            float m = fmaxf(fmaxf(s0, s1), fmaxf(s2, s3));
            m = fmaxf(m, __shfl_xor(m, 1));
            m = fmaxf(m, __shfl_xor(m, 2));
            m = fmaxf(m, __shfl_xor(m, 4));
            m = fmaxf(m, __shfl_xor(m, 8));
            float p0 = __expf(s0 - m), p1 = __expf(s1 - m);
            float p2 = __expf(s2 - m), p3 = __expf(s3 - m);
            float s = (p0 + p1) + (p2 + p3);
            s += __shfl_xor(s, 1);
            s += __shfl_xor(s, 2);
            s += __shfl_xor(s, 4);
            s += __shfl_xor(s, 8);
            float inv = __builtin_amdgcn_rcpf(s);
            int rl = lk * 4 + e;
            Pw[rl * 72 + lr]      = (bf16)(p0 * inv);
            Pw[rl * 72 + 16 + lr] = (bf16)(p1 * inv);
            Pw[rl * 72 + 32 + lr] = (bf16)(p2 * inv);
            Pw[rl * 72 + 48 + lr] = (bf16)(p3 * inv);
        }
        asm volatile("s_waitcnt lgkmcnt(0)" ::: "memory");
        // PV: Ostrip_h += Pstrip @ V_h  (4 MFMA)
#pragma unroll
        for (int kk = 0; kk < 2; ++kk) {
            bf16x8 pa = *(const bf16x8*)&Pw[lr * 72 + kk * 32 + lk * 8];
#pragma unroll
            for (int ni = 0; ni < 2; ++ni) {
                bf16x8 vb = *(const bf16x8*)&vt[(h * 32 + ni * 16 + lr) * 72 + kk * 32 + lk * 8];
                oacc[h][ni] = __builtin_amdgcn_mfma_f32_16x16x32_bf16(pa, vb, oacc[h][ni], 0, 0, 0);
            }
        }
    }

    // ---- O -> LDS (overlay qall; only own strip rows, in-wave ordered)
#pragma unroll
    for (int h = 0; h < 3; ++h)
#pragma unroll
        for (int ni = 0; ni < 2; ++ni)
#pragma unroll
            for (int e = 0; e < 4; ++e)
                Ost[(w * 16 + lk * 4 + e) * 104 + h * 32 + ni * 16 + lr]
                    = (bf16)oacc[h][ni][e];
    __syncthreads();

    // ---- proj: [64x96]@[96x96]; wave w: strip mi=w, 6 ni tiles. 18 MFMA.
    {
        f32x4 pacc[6];
#pragma unroll
        for (int ni = 0; ni < 6; ++ni) pacc[ni] = (f32x4){0.f, 0.f, 0.f, 0.f};
#pragma unroll
        for (int k = 0; k < 3; ++k) {
            bf16x8 a = *(const bf16x8*)&Ost[(w * 16 + lr) * 104 + k * 32 + lk * 8];
#pragma unroll
            for (int ni = 0; ni < 6; ++ni) {
                bf16x8 wb = *(const bf16x8*)&woutT[(ni * 16 + lr) * 96 + k * 32 + lk * 8];
                pacc[ni] = __builtin_amdgcn_mfma_f32_16x16x32_bf16(a, wb, pacc[ni], 0, 0, 0);
            }
        }
#pragma unroll
        for (int ni = 0; ni < 6; ++ni)
#pragma unroll
            for (int e = 0; e < 4; ++e) {
                int t = w * 16 + lk * 4 + e;
                fin[t * 101 + ni * 16 + lr] = pacc[ni][e] + bo[ni];
            }
    }
    __syncthreads();

    // ---- store [b, c, H, W]
    for (int i = tid; i < 49 * 96; i += 256) {
        int c = i / 49, t = i - c * 49;
        out[((size_t)(b * 96 + c)) * 3136 + (row0 + t / 7) * 56 + col0 + t % 7]
            = fin[t * 101 + c];
    }
}

extern "C" void kernel_launch(void* const* d_in, const int* in_sizes, int n_in,
                              void* d_out, int out_size, void* d_ws, size_t ws_size,
                              hipStream_t stream) {
    const float* x    = (const float*)d_in[0];
    const float* wqkv = (const float*)d_in[1];
    const float* pos  = (const float*)d_in[2];
    const float* wout = (const float*)d_in[3];
    const float* bout = (const float*)d_in[4];
    float* outp = (float*)d_out;

    bf16*  xwin  = (bf16*)((char*)d_ws + XWIN_OFF);
    bf16*  wqkvT = (bf16*)((char*)d_ws + WQKVT_OFF);
    bf16*  woutT = (bf16*)((char*)d_ws + WOUTT_OFF);
    float* biasw = (float*)((char*)d_ws + BIAS_OFF);

    pre<<<dim3(516), dim3(512), 0, stream>>>(x, wqkv, pos, wout,
                                             xwin, wqkvT, woutT, biasw);
    winattn<<<dim3(4096), dim3(256), 0, stream>>>(xwin, bout, wqkvT, woutT,
                                                  biasw, outp);
}

// Round 10
// 133.046 us; speedup vs baseline: 1.3247x; 1.1342x over previous
//
#include <hip/hip_runtime.h>

typedef __bf16 bf16;
typedef __bf16 bf16x4 __attribute__((ext_vector_type(4)));
typedef __bf16 bf16x8 __attribute__((ext_vector_type(8)));
typedef float  f32x4  __attribute__((ext_vector_type(4)));

#define SCALE 0.17677669529663687f  // 32^-0.5

// ws layout (bytes)
#define XWIN_OFF  0                  // bf16 [64 b][64 win][64 tok][96 ch]
#define WQKVT_OFF 50331648           // bf16 [288][96] (q cols pre-scaled)
#define WOUTT_OFF 50386944           // bf16 [96][96] transposed
#define BIASC_OFF 50405376           // f32 [3 h][4 ni][4 w][64 lane][4 e] C-frag layout

#define FENCE_LDS() do { asm volatile("s_waitcnt lgkmcnt(0)" ::: "memory"); \
                         __builtin_amdgcn_sched_barrier(0); } while (0)

// ---- im2win (blocks 0..511) + weight/bias prep (blocks 512..515)
__global__ __launch_bounds__(512)
void pre(const float* __restrict__ x, const float* __restrict__ wqkv,
         const float* __restrict__ pos, const float* __restrict__ wout,
         bf16* __restrict__ xwin, bf16* __restrict__ wqkvT,
         bf16* __restrict__ woutT, float* __restrict__ biasC)
{
    __shared__ bf16 xs[392 * 50];
    if (blockIdx.x < 512) {
        const int tid = threadIdx.x;
        const int b = blockIdx.x >> 3, wh = blockIdx.x & 7;
        const float* xb = x + (size_t)b * 96 * 3136 + wh * 7 * 56;
        bf16* xo = xwin + ((size_t)b * 64 + wh * 8) * 64 * 96;
        for (int c0 = 0; c0 < 96; c0 += 48) {
            if (c0) __syncthreads();
            for (int i = tid; i < 48 * 392; i += 512) {
                int c = i / 392, t = i - c * 392;
                xs[t * 50 + c] = (bf16)xb[(size_t)(c0 + c) * 3136 + t];
            }
            __syncthreads();
            for (int i = tid; i < 8 * 64 * 48; i += 512) {
                int c = i % 48;
                int wt = (i / 48) & 63;
                int win = i / (48 * 64);
                bf16 v = (bf16)0.f;
                if (wt < 49) v = xs[((wt / 7) * 56 + win * 7 + (wt % 7)) * 50 + c];
                xo[(win * 64 + wt) * 96 + c0 + c] = v;
            }
        }
    } else {
        int tid = (blockIdx.x - 512) * 512 + threadIdx.x;
        const int stride = 4 * 512;
        for (int i = tid; i < 288 * 96; i += stride) {
            int n = i / 96, c = i % 96;
            float v = wqkv[c * 288 + n];
            if (n < 96) v *= SCALE;
            wqkvT[i] = (bf16)v;
        }
        for (int i = tid; i < 96 * 96; i += stride) {
            int o = i / 96, c = i % 96;
            woutT[i] = (bf16)wout[c * 96 + o];
        }
        // biasC[h][ni][w][lane][e] = bias value at row=w*16+(lane>>4)*4+e, col=ni*16+(lane&15)
        for (int i = tid; i < 3 * 4 * 4 * 64 * 4; i += stride) {
            int e = i & 3, lane = (i >> 2) & 63, wv = (i >> 8) & 3, ni = (i >> 10) & 3, h = i >> 12;
            int row = wv * 16 + ((lane >> 4) << 2) + e;
            int col = ni * 16 + (lane & 15);
            float v;
            if (col >= 49) v = -1e30f;
            else if (row >= 49) v = 0.f;
            else {
                int ridx = ((col / 7) - (row / 7) + 6) * 13 + ((col % 7) - (row % 7) + 6);
                v = pos[ridx * 3 + h];
            }
            biasC[i] = v;
        }
    }
}

// One block (4 waves) per window; wave w owns token strip w*16..+15.
// LDS 40448 B -> 4 blocks/CU. 3 barriers.
__global__ __launch_bounds__(256, 4)
void winattn(const bf16* __restrict__ xwin, const float* __restrict__ bout,
             const bf16* __restrict__ wqkvT, const bf16* __restrict__ woutT,
             const float* __restrict__ biasC, float* __restrict__ out)
{
    __shared__ __align__(16) unsigned char smem[40448];
    bf16* qall = (bf16*)(smem);          // [64][104]
    bf16* kall = (bf16*)(smem + 13312);  // [64][104]
    bf16* vt   = (bf16*)(smem + 26624);  // [96][72]
    bf16* Ost  = (bf16*)(smem);          // overlay qall (own strip only)
    float* fin = (float*)(smem + 13312); // [64][101] f32, overlays kall+vt (post-B2)

    const int tid = threadIdx.x;
    const int w = tid >> 6, lane = tid & 63;
    const int lr = lane & 15, lk = lane >> 4;

    const int blk = blockIdx.x;
    const int b = blk >> 6, win = blk & 63;
    const int row0 = (win >> 3) * 7, col0 = (win & 7) * 7;
    const bf16* xg = xwin + (size_t)blk * 64 * 96;

    float bo[6];
#pragma unroll
    for (int ni = 0; ni < 6; ++ni) bo[ni] = bout[ni * 16 + lr];

    // ---- QKV: wave w = row strip; 3 groups of 6 ni tiles (g0=q, g1=k, g2=v)
    {
        bf16x8 a[3];
#pragma unroll
        for (int k = 0; k < 3; ++k)
            a[k] = *(const bf16x8*)&xg[(w * 16 + lr) * 96 + k * 32 + lk * 8];
#pragma unroll
        for (int g = 0; g < 3; ++g) {
            f32x4 acc[6];
#pragma unroll
            for (int j = 0; j < 6; ++j) acc[j] = (f32x4){0.f, 0.f, 0.f, 0.f};
#pragma unroll
            for (int k = 0; k < 3; ++k)
#pragma unroll
                for (int j = 0; j < 6; ++j) {
                    bf16x8 bb = *(const bf16x8*)&wqkvT[((g * 6 + j) * 16 + lr) * 96 + k * 32 + lk * 8];
                    acc[j] = __builtin_amdgcn_mfma_f32_16x16x32_bf16(a[k], bb, acc[j], 0, 0, 0);
                }
            if (g == 0) {
#pragma unroll
                for (int j = 0; j < 6; ++j)
#pragma unroll
                    for (int e = 0; e < 4; ++e)
                        qall[(w * 16 + lk * 4 + e) * 104 + j * 16 + lr] = (bf16)acc[j][e];
            } else if (g == 1) {
#pragma unroll
                for (int j = 0; j < 6; ++j)
#pragma unroll
                    for (int e = 0; e < 4; ++e)
                        kall[(w * 16 + lk * 4 + e) * 104 + j * 16 + lr] = (bf16)acc[j][e];
            } else {
#pragma unroll
                for (int j = 0; j < 6; ++j) {
                    bf16x4 pk;
#pragma unroll
                    for (int e = 0; e < 4; ++e) pk[e] = (bf16)acc[j][e];
                    *(bf16x4*)&vt[(j * 16 + lr) * 72 + w * 16 + lk * 4] = pk;
                }
            }
        }
    }
    // prefetch head-0 bias C-frags (latency covered by barrier)
    f32x4 bias0[4], bias1[4], bias2[4];
#pragma unroll
    for (int ni = 0; ni < 4; ++ni)
        bias0[ni] = *(const f32x4*)&biasC[(size_t)((0 * 4 + ni) * 4 + w) * 256 + lane * 4];
    __syncthreads();   // B1

    // ---- read Q A-frags for all heads, then P may overlay own qall strip
    bf16x8 qa[3];
#pragma unroll
    for (int h = 0; h < 3; ++h)
        qa[h] = *(const bf16x8*)&qall[(w * 16 + lr) * 104 + h * 32 + lk * 8];
    FENCE_LDS();

    bf16* Pw = (bf16*)(smem + w * 3328);   // [16][72] inside own qall strip

    f32x4 oacc[3][2];
#pragma unroll
    for (int h = 0; h < 3; ++h)
#pragma unroll
        for (int ni = 0; ni < 2; ++ni) oacc[h][ni] = (f32x4){0.f, 0.f, 0.f, 0.f};

#pragma unroll
    for (int h = 0; h < 3; ++h) {
        // S = Q@K^T + bias (bias is the C-operand)
        f32x4 sacc[4];
        const f32x4* bc = (h == 0) ? bias0 : (h == 1) ? bias1 : bias2;
#pragma unroll
        for (int ni = 0; ni < 4; ++ni) {
            bf16x8 kb = *(const bf16x8*)&kall[(ni * 16 + lr) * 104 + h * 32 + lk * 8];
            sacc[ni] = __builtin_amdgcn_mfma_f32_16x16x32_bf16(qa[h], kb, bc[ni], 0, 0, 0);
        }
        // prefetch next head's bias (covered by softmax+PV)
        if (h == 0) {
#pragma unroll
            for (int ni = 0; ni < 4; ++ni)
                bias1[ni] = *(const f32x4*)&biasC[(size_t)((1 * 4 + ni) * 4 + w) * 256 + lane * 4];
        } else if (h == 1) {
#pragma unroll
            for (int ni = 0; ni < 4; ++ni)
                bias2[ni] = *(const f32x4*)&biasC[(size_t)((2 * 4 + ni) * 4 + w) * 256 + lane * 4];
        }
        // softmax (rows lk*4+e, cols lr + 16*ni)
#pragma unroll
        for (int e = 0; e < 4; ++e) {
            float s0 = sacc[0][e], s1 = sacc[1][e], s2 = sacc[2][e], s3 = sacc[3][e];
            float m = fmaxf(fmaxf(s0, s1), fmaxf(s2, s3));
            m = fmaxf(m, __shfl_xor(m, 1));
            m = fmaxf(m, __shfl_xor(m, 2));
            m = fmaxf(m, __shfl_xor(m, 4));
            m = fmaxf(m, __shfl_xor(m, 8));
            float p0 = __expf(s0 - m), p1 = __expf(s1 - m);
            float p2 = __expf(s2 - m), p3 = __expf(s3 - m);
            float s = (p0 + p1) + (p2 + p3);
            s += __shfl_xor(s, 1);
            s += __shfl_xor(s, 2);
            s += __shfl_xor(s, 4);
            s += __shfl_xor(s, 8);
            float inv = __builtin_amdgcn_rcpf(s);
            int rl = lk * 4 + e;
            Pw[rl * 72 + lr]      = (bf16)(p0 * inv);
            Pw[rl * 72 + 16 + lr] = (bf16)(p1 * inv);
            Pw[rl * 72 + 32 + lr] = (bf16)(p2 * inv);
            Pw[rl * 72 + 48 + lr] = (bf16)(p3 * inv);
        }
        FENCE_LDS();
        // PV: Ostrip_h += Pstrip @ V_h
#pragma unroll
        for (int kk = 0; kk < 2; ++kk) {
            bf16x8 pa = *(const bf16x8*)&Pw[lr * 72 + kk * 32 + lk * 8];
#pragma unroll
            for (int ni = 0; ni < 2; ++ni) {
                bf16x8 vb = *(const bf16x8*)&vt[(h * 32 + ni * 16 + lr) * 72 + kk * 32 + lk * 8];
                oacc[h][ni] = __builtin_amdgcn_mfma_f32_16x16x32_bf16(pa, vb, oacc[h][ni], 0, 0, 0);
            }
        }
    }
    FENCE_LDS();

    // ---- O -> Ost (overlay qall, own strip only)
#pragma unroll
    for (int h = 0; h < 3; ++h)
#pragma unroll
        for (int ni = 0; ni < 2; ++ni)
#pragma unroll
            for (int e = 0; e < 4; ++e)
                Ost[(w * 16 + lk * 4 + e) * 104 + h * 32 + ni * 16 + lr]
                    = (bf16)oacc[h][ni][e];
    __syncthreads();   // B2 (protects kall/vt for fin overlay; drains Ost writes)

    // ---- proj: wave strip x [96x96]; 18 MFMA; fin overlays kall+vt
    {
        f32x4 pacc[6];
#pragma unroll
        for (int ni = 0; ni < 6; ++ni) pacc[ni] = (f32x4){0.f, 0.f, 0.f, 0.f};
#pragma unroll
        for (int k = 0; k < 3; ++k) {
            bf16x8 a = *(const bf16x8*)&Ost[(w * 16 + lr) * 104 + k * 32 + lk * 8];
#pragma unroll
            for (int ni = 0; ni < 6; ++ni) {
                bf16x8 wb = *(const bf16x8*)&woutT[(ni * 16 + lr) * 96 + k * 32 + lk * 8];
                pacc[ni] = __builtin_amdgcn_mfma_f32_16x16x32_bf16(a, wb, pacc[ni], 0, 0, 0);
            }
        }
#pragma unroll
        for (int ni = 0; ni < 6; ++ni)
#pragma unroll
            for (int e = 0; e < 4; ++e)
                fin[(w * 16 + lk * 4 + e) * 101 + ni * 16 + lr] = pacc[ni][e] + bo[ni];
    }
    __syncthreads();   // B3

    // ---- store [b, c, H, W]; t = lane fixed, channel marches
    {
        const int t = lane;
        if (t < 49) {
            const int off = (row0 + t / 7) * 56 + col0 + t % 7;
            float* ob = out + (size_t)(b * 96 + w * 24) * 3136 + off;
            const float* fr = fin + t * 101 + w * 24;
#pragma unroll
            for (int j = 0; j < 24; ++j)
                ob[(size_t)j * 3136] = fr[j];
        }
    }
}

extern "C" void kernel_launch(void* const* d_in, const int* in_sizes, int n_in,
                              void* d_out, int out_size, void* d_ws, size_t ws_size,
                              hipStream_t stream) {
    const float* x    = (const float*)d_in[0];
    const float* wqkv = (const float*)d_in[1];
    const float* pos  = (const float*)d_in[2];
    const float* wout = (const float*)d_in[3];
    const float* bout = (const float*)d_in[4];
    float* outp = (float*)d_out;

    bf16*  xwin  = (bf16*)((char*)d_ws + XWIN_OFF);
    bf16*  wqkvT = (bf16*)((char*)d_ws + WQKVT_OFF);
    bf16*  woutT = (bf16*)((char*)d_ws + WOUTT_OFF);
    float* biasC = (float*)((char*)d_ws + BIASC_OFF);

    pre<<<dim3(516), dim3(512), 0, stream>>>(x, wqkv, pos, wout,
                                             xwin, wqkvT, woutT, biasC);
    winattn<<<dim3(4096), dim3(256), 0, stream>>>(xwin, bout, wqkvT, woutT,
                                                  biasC, outp);
}